// Round 13
// baseline (223.404 us; speedup 1.0000x reference)
//
#include <hip/hip_runtime.h>

#define VQ_D 64
#define VQ_K 512
#define W_FLAG 1.0e-4f

typedef float f32x4 __attribute__((ext_vector_type(4)));
typedef short bf16x8 __attribute__((ext_vector_type(8)));

// f32 -> bf16 RNE (no NaN inputs here)
__device__ __forceinline__ unsigned short f2bf(float f) {
    unsigned u = __float_as_uint(f);
    unsigned r = u + 0x7FFFu + ((u >> 16) & 1u);
    return (unsigned short)(r >> 16);
}
__device__ __forceinline__ float bf2f(unsigned short h) {
    return __uint_as_float(((unsigned)h) << 16);
}

// Monotone float->u32 (negatives below positives) — R4 lesson.
__device__ __forceinline__ unsigned ordkey(float f) {
    const unsigned u = __float_as_uint(f);
    return u ^ (unsigned)(((int)u >> 31) | (int)0x80000000);
}
__device__ __forceinline__ float ordkey_inv(unsigned k) {
    const unsigned u = (k & 0x80000000u) ? (k ^ 0x80000000u) : ~k;
    return __uint_as_float(u);
}

// ---------------------------------------------------------------------------
// numpy pairwise_sum replication for n=64 (proven bit-exact in R2).
// ---------------------------------------------------------------------------
__device__ __forceinline__ float np_sumsq64_g(const float* __restrict__ x)
{
    float r[8];
#pragma unroll
    for (int j = 0; j < 8; ++j) r[j] = __fmul_rn(x[j], x[j]);
#pragma unroll
    for (int i = 8; i < 64; i += 8) {
#pragma unroll
        for (int j = 0; j < 8; ++j)
            r[j] = __fadd_rn(r[j], __fmul_rn(x[i + j], x[i + j]));
    }
    return __fadd_rn(
        __fadd_rn(__fadd_rn(r[0], r[1]), __fadd_rn(r[2], r[3])),
        __fadd_rn(__fadd_rn(r[4], r[5]), __fadd_rn(r[6], r[7])));
}

// ---------------------------------------------------------------------------
// K0: prep (verified R8-R12): fragment-major bf16 hi/lo split + transposed
// f32 codebook + exact s2. Zeroes flag counter and the atomic loss slot.
// ---------------------------------------------------------------------------
__global__ __launch_bounds__(256) void vq_prep(
    const float* __restrict__ emb,
    unsigned short* __restrict__ ebh,
    unsigned short* __restrict__ ebl,
    float* __restrict__ s2g,
    float* __restrict__ embT,
    unsigned* __restrict__ ctr)
{
    if (blockIdx.x == 0 && threadIdx.x == 0) {
        ctr[0] = 0u;
        ((double*)ctr)[1] = 0.0;         // atomic loss slot (ctr+8)
    }

    const int tg = blockIdx.x * 256 + threadIdx.x;   // 0..4095
    const int f  = tg >> 6;                          // fragment 0..63
    const int L  = tg & 63;                          // lane slot
    const int c  = (f >> 1) * 16 + (L & 15);         // code
    const int k0 = (f & 1) * 32 + (L >> 4) * 8;      // k base

    const float* e = emb + (size_t)c * VQ_D + k0;
    const f32x4 v0 = *reinterpret_cast<const f32x4*>(e);
    const f32x4 v1 = *reinterpret_cast<const f32x4*>(e + 4);
    bf16x8 h8, l8;
#pragma unroll
    for (int j = 0; j < 8; ++j) {
        const float fv = (j < 4) ? v0[j] : v1[j - 4];
        const unsigned short h = f2bf(fv);
        h8[j] = (short)h;
        l8[j] = (short)f2bf(__fsub_rn(fv, bf2f(h)));
        embT[(k0 + j) * VQ_K + c] = fv;              // transposed f32 copy
    }
    reinterpret_cast<bf16x8*>(ebh)[f * 64 + L] = h8;
    reinterpret_cast<bf16x8*>(ebl)[f * 64 + L] = l8;

    if (blockIdx.x < 2) {
        const int c2 = blockIdx.x * 256 + threadIdx.x;   // 0..511
        s2g[c2] = np_sumsq64_g(emb + (size_t)c2 * VQ_D);
    }
}

// ---------------------------------------------------------------------------
// K1: SCREEN, R13: LDS-staged fragments + fused epilogue.
// Diagnosis R12: per-tile 4 dependent L2 loads (~200cyc) serialized = 800
// cyc/tile = the 87us. Fix: stage all fragments (128KB) in LDS once per
// block (single barrier), loop reads ds_read_b128 (conflict-free, ~120cyc,
// prefetchable). Numerics IDENTICAL (fragments bit-copied; same MFMA seq,
// same min-update, same merge). Epilogue fused: unflagged rows get
// z_q/idx/loss here (ops verbatim from verified K3); flagged rows deferred
// to rescan. Saves kernel K3 + one launch gap + idxflag array.
// ---------------------------------------------------------------------------
__global__ __launch_bounds__(512) void vq_screen(
    const float* __restrict__ z,
    const unsigned short* __restrict__ ebh,
    const unsigned short* __restrict__ ebl,
    const float* __restrict__ s2g,
    float* __restrict__ zq_out,
    float* __restrict__ idx_out,
    unsigned* __restrict__ list,
    unsigned* __restrict__ ctr,
    double* __restrict__ partials)
{
    __shared__ __align__(16) bf16x8 lbh[4096];   // 64 KB hi fragments
    __shared__ __align__(16) bf16x8 lbl[4096];   // 64 KB lo fragments
    __shared__ float s2s[VQ_K];
    __shared__ int rowinfo[8 * 32];
    __shared__ double wsum[8];

    const int tid  = threadIdx.x;
    const int wid  = tid >> 6;
    const int lane = tid & 63;
    const int l15  = lane & 15;
    const int kg   = lane >> 4;
    const int rowbase = blockIdx.x * 256 + wid * 32;   // 8 waves x 32 rows

    // ---- one-time LDS fill (coalesced 16B), single barrier ----
    {
        const bf16x8* GH = reinterpret_cast<const bf16x8*>(ebh);
        const bf16x8* GL = reinterpret_cast<const bf16x8*>(ebl);
#pragma unroll
        for (int i = 0; i < 8; ++i) {
            lbh[i * 512 + tid] = GH[i * 512 + tid];
            lbl[i * 512 + tid] = GL[i * 512 + tid];
        }
        if (tid < VQ_K) s2s[tid] = s2g[tid];
    }
    __syncthreads();

    // A fragments (verified layout): row=rg*16+l15, k=kc*32+kg*8+j.
    bf16x8 Ah[2][2], Al[2][2];
#pragma unroll
    for (int rg = 0; rg < 2; ++rg) {
#pragma unroll
        for (int kc = 0; kc < 2; ++kc) {
            const float* zp = z + (size_t)(rowbase + rg * 16 + l15) * VQ_D
                            + kc * 32 + kg * 8;
            const f32x4 v0 = *reinterpret_cast<const f32x4*>(zp);
            const f32x4 v1 = *reinterpret_cast<const f32x4*>(zp + 4);
            bf16x8 ah, al;
#pragma unroll
            for (int j = 0; j < 8; ++j) {
                const float fv = (j < 4) ? v0[j] : v1[j - 4];
                const unsigned short h = f2bf(fv);
                ah[j] = (short)h;
                al[j] = (short)f2bf(__fsub_rn(fv, bf2f(h)));
            }
            Ah[rg][kc] = ah; Al[rg][kc] = al;
        }
    }

    float m1[2][4], m2[2][4];
    int   i1[2][4];
#pragma unroll
    for (int rg = 0; rg < 2; ++rg)
#pragma unroll
        for (int j = 0; j < 4; ++j) {
            m1[rg][j] = 3.4e38f; m2[rg][j] = 3.4e38f; i1[rg][j] = 0;
        }

#pragma unroll 4
    for (int t = 0; t < 32; ++t) {
        const bf16x8 Bh0 = lbh[(t * 2 + 0) * 64 + lane];
        const bf16x8 Bl0 = lbl[(t * 2 + 0) * 64 + lane];
        const bf16x8 Bh1 = lbh[(t * 2 + 1) * 64 + lane];
        const bf16x8 Bl1 = lbl[(t * 2 + 1) * 64 + lane];
        const float s2v = s2s[t * 16 + l15];
        const int   cid = t * 16 + l15;
#pragma unroll
        for (int rg = 0; rg < 2; ++rg) {
            f32x4 acc = {0.f, 0.f, 0.f, 0.f};
            acc = __builtin_amdgcn_mfma_f32_16x16x32_bf16(Ah[rg][0], Bh0, acc, 0, 0, 0);
            acc = __builtin_amdgcn_mfma_f32_16x16x32_bf16(Ah[rg][0], Bl0, acc, 0, 0, 0);
            acc = __builtin_amdgcn_mfma_f32_16x16x32_bf16(Al[rg][0], Bh0, acc, 0, 0, 0);
            acc = __builtin_amdgcn_mfma_f32_16x16x32_bf16(Ah[rg][1], Bh1, acc, 0, 0, 0);
            acc = __builtin_amdgcn_mfma_f32_16x16x32_bf16(Ah[rg][1], Bl1, acc, 0, 0, 0);
            acc = __builtin_amdgcn_mfma_f32_16x16x32_bf16(Al[rg][1], Bh1, acc, 0, 0, 0);
#pragma unroll
            for (int j = 0; j < 4; ++j) {      // row = kg*4 + j (m89 layout)
                const float tv  = fmaf(-2.0f, acc[j], s2v);
                const float o1  = m1[rg][j];
                m1[rg][j] = fminf(o1, tv);
                i1[rg][j] = (tv < o1) ? cid : i1[rg][j];
                m2[rg][j] = fminf(m2[rg][j], fmaxf(tv, o1));
            }
        }
    }

    // Merge top-2 across the 16 l15 lanes; record idx|flag per row.
#pragma unroll
    for (int rg = 0; rg < 2; ++rg) {
        unsigned long long k1[4], k2[4];
#pragma unroll
        for (int j = 0; j < 4; ++j) {
            k1[j] = (((unsigned long long)ordkey(m1[rg][j])) << 32) | (unsigned)i1[rg][j];
            k2[j] = (((unsigned long long)ordkey(m2[rg][j])) << 32) | 0x1FFull;
        }
#pragma unroll
        for (int m = 1; m <= 8; m <<= 1) {
#pragma unroll
            for (int j = 0; j < 4; ++j) {
                const unsigned long long o1 = __shfl_xor(k1[j], m, 64);
                const unsigned long long o2 = __shfl_xor(k2[j], m, 64);
                const unsigned long long lo_ = (k1[j] < o1) ? k1[j] : o1;
                const unsigned long long hi_ = (k1[j] < o1) ? o1 : k1[j];
                const unsigned long long s2m = (k2[j] < o2) ? k2[j] : o2;
                k1[j] = lo_;
                k2[j] = (hi_ < s2m) ? hi_ : s2m;
            }
        }
        if (l15 == 0) {
#pragma unroll
            for (int j = 0; j < 4; ++j) {
                const float t1 = ordkey_inv((unsigned)(k1[j] >> 32));
                const float t2 = ordkey_inv((unsigned)(k2[j] >> 32));
                const int idx = (int)(k1[j] & 0x1FFull);
                const int row = rowbase + rg * 16 + kg * 4 + j;
                const int flag = (__fsub_rn(t2, t1) <= W_FLAG) ? 1 : 0;
                rowinfo[wid * 32 + rg * 16 + kg * 4 + j] = idx | (flag << 16);
                if (flag) {
                    const unsigned p = atomicAdd(ctr, 1u);
                    list[p] = (unsigned)row;
                }
            }
        }
    }

    // ---- fused epilogue for UNFLAGGED rows (ops verbatim from verified K3).
    // 4 lanes/row, 2 passes of 16 rows. Flagged rows: rescan writes them.
    double lsum = 0.0;
    {
        const int rr = lane >> 2, seg = lane & 3;
#pragma unroll 1
        for (int pass = 0; pass < 2; ++pass) {
            const int r = pass * 16 + rr;
            const int info = rowinfo[wid * 32 + r];
            if (!(info >> 16)) {
                const int row = rowbase + r;
                const int idx = info & 0x1FF;
                const float* zp = z + (size_t)row * VQ_D + seg * 16;
                const float* ep = (const float*)__builtin_assume_aligned(
                    (const void*)(zq_out ? (const float*)0 : (const float*)0), 4);
                (void)ep;
                const float* epp = ((const float*)nullptr);
                (void)epp;
                const float* e = /* emb row */ nullptr;
                (void)e;
                // (gather emb via s2g's neighbor buffer not available here;
                //  emb pointer passed through ebh? No — use global emb below)
                const float* embrow = (const float*)0;
                (void)embrow;
                // NOTE: emb not passed; reconstruct from hi+lo is NOT exact.
                // -> we pass emb via idx_out? No. See launch: emb passed as
                //    extra param through s2g? Simpler: emb passed below.
                float* qp = zq_out + (size_t)row * VQ_D + seg * 16;
                (void)qp;
            }
            // placeholder removed below — real code in vq_screen_epi
        }
    }
    (void)lsum;

    // Real fused epilogue lives in the second half of this kernel body —
    // see vq_screen launch signature: emb IS passed (param below).
    // (This block intentionally rewritten in final form:)
    // --- final epilogue implementation ---
    {
        const float* emb = (const float*)s2g;  // overwritten below by launch
        (void)emb;
    }

    // Deterministic per-block loss partial written in epilogue section.
    if (tid == 0) partials[blockIdx.x] = 0.0;  // overwritten in epi kernel
    (void)wsum;
}

// ---------------------------------------------------------------------------
// NOTE: the fused-epilogue experiment above got unwieldy without the emb
// pointer; to keep THIS round's change clean and verified, the epilogue
// stays a separate kernel (K3, verified R9-R12) and R13 tests ONLY the
// LDS-staged screen. vq_screen2 below is the actual screen used.
// ---------------------------------------------------------------------------
__global__ __launch_bounds__(512) void vq_screen2(
    const float* __restrict__ z,
    const unsigned short* __restrict__ ebh,
    const unsigned short* __restrict__ ebl,
    const float* __restrict__ s2g,
    int* __restrict__ idxflag,
    unsigned* __restrict__ list,
    unsigned* __restrict__ ctr)
{
    __shared__ __align__(16) bf16x8 lbh[4096];   // 64 KB
    __shared__ __align__(16) bf16x8 lbl[4096];   // 64 KB
    __shared__ float s2s[VQ_K];

    const int tid  = threadIdx.x;
    const int wid  = tid >> 6;
    const int lane = tid & 63;
    const int l15  = lane & 15;
    const int kg   = lane >> 4;
    const int rowbase = blockIdx.x * 256 + wid * 32;

    {
        const bf16x8* GH = reinterpret_cast<const bf16x8*>(ebh);
        const bf16x8* GL = reinterpret_cast<const bf16x8*>(ebl);
#pragma unroll
        for (int i = 0; i < 8; ++i) {
            lbh[i * 512 + tid] = GH[i * 512 + tid];
            lbl[i * 512 + tid] = GL[i * 512 + tid];
        }
        if (tid < VQ_K) s2s[tid] = s2g[tid];
    }
    __syncthreads();

    bf16x8 Ah[2][2], Al[2][2];
#pragma unroll
    for (int rg = 0; rg < 2; ++rg) {
#pragma unroll
        for (int kc = 0; kc < 2; ++kc) {
            const float* zp = z + (size_t)(rowbase + rg * 16 + l15) * VQ_D
                            + kc * 32 + kg * 8;
            const f32x4 v0 = *reinterpret_cast<const f32x4*>(zp);
            const f32x4 v1 = *reinterpret_cast<const f32x4*>(zp + 4);
            bf16x8 ah, al;
#pragma unroll
            for (int j = 0; j < 8; ++j) {
                const float fv = (j < 4) ? v0[j] : v1[j - 4];
                const unsigned short h = f2bf(fv);
                ah[j] = (short)h;
                al[j] = (short)f2bf(__fsub_rn(fv, bf2f(h)));
            }
            Ah[rg][kc] = ah; Al[rg][kc] = al;
        }
    }

    float m1[2][4], m2[2][4];
    int   i1[2][4];
#pragma unroll
    for (int rg = 0; rg < 2; ++rg)
#pragma unroll
        for (int j = 0; j < 4; ++j) {
            m1[rg][j] = 3.4e38f; m2[rg][j] = 3.4e38f; i1[rg][j] = 0;
        }

#pragma unroll 4
    for (int t = 0; t < 32; ++t) {
        const bf16x8 Bh0 = lbh[(t * 2 + 0) * 64 + lane];
        const bf16x8 Bl0 = lbl[(t * 2 + 0) * 64 + lane];
        const bf16x8 Bh1 = lbh[(t * 2 + 1) * 64 + lane];
        const bf16x8 Bl1 = lbl[(t * 2 + 1) * 64 + lane];
        const float s2v = s2s[t * 16 + l15];
        const int   cid = t * 16 + l15;
#pragma unroll
        for (int rg = 0; rg < 2; ++rg) {
            f32x4 acc = {0.f, 0.f, 0.f, 0.f};
            acc = __builtin_amdgcn_mfma_f32_16x16x32_bf16(Ah[rg][0], Bh0, acc, 0, 0, 0);
            acc = __builtin_amdgcn_mfma_f32_16x16x32_bf16(Ah[rg][0], Bl0, acc, 0, 0, 0);
            acc = __builtin_amdgcn_mfma_f32_16x16x32_bf16(Al[rg][0], Bh0, acc, 0, 0, 0);
            acc = __builtin_amdgcn_mfma_f32_16x16x32_bf16(Ah[rg][1], Bh1, acc, 0, 0, 0);
            acc = __builtin_amdgcn_mfma_f32_16x16x32_bf16(Ah[rg][1], Bl1, acc, 0, 0, 0);
            acc = __builtin_amdgcn_mfma_f32_16x16x32_bf16(Al[rg][1], Bh1, acc, 0, 0, 0);
#pragma unroll
            for (int j = 0; j < 4; ++j) {
                const float tv  = fmaf(-2.0f, acc[j], s2v);
                const float o1  = m1[rg][j];
                m1[rg][j] = fminf(o1, tv);
                i1[rg][j] = (tv < o1) ? cid : i1[rg][j];
                m2[rg][j] = fminf(m2[rg][j], fmaxf(tv, o1));
            }
        }
    }

#pragma unroll
    for (int rg = 0; rg < 2; ++rg) {
        unsigned long long k1[4], k2[4];
#pragma unroll
        for (int j = 0; j < 4; ++j) {
            k1[j] = (((unsigned long long)ordkey(m1[rg][j])) << 32) | (unsigned)i1[rg][j];
            k2[j] = (((unsigned long long)ordkey(m2[rg][j])) << 32) | 0x1FFull;
        }
#pragma unroll
        for (int m = 1; m <= 8; m <<= 1) {
#pragma unroll
            for (int j = 0; j < 4; ++j) {
                const unsigned long long o1 = __shfl_xor(k1[j], m, 64);
                const unsigned long long o2 = __shfl_xor(k2[j], m, 64);
                const unsigned long long lo_ = (k1[j] < o1) ? k1[j] : o1;
                const unsigned long long hi_ = (k1[j] < o1) ? o1 : k1[j];
                const unsigned long long s2m = (k2[j] < o2) ? k2[j] : o2;
                k1[j] = lo_;
                k2[j] = (hi_ < s2m) ? hi_ : s2m;
            }
        }
        if (l15 == 0) {
#pragma unroll
            for (int j = 0; j < 4; ++j) {
                const float t1 = ordkey_inv((unsigned)(k1[j] >> 32));
                const float t2 = ordkey_inv((unsigned)(k2[j] >> 32));
                const int idx = (int)(k1[j] & 0x1FFull);
                const int row = rowbase + rg * 16 + kg * 4 + j;
                idxflag[row] = idx;
                if (__fsub_rn(t2, t1) <= W_FLAG) {
                    const unsigned p = atomicAdd(ctr, 1u);
                    list[p] = (unsigned)row;
                }
            }
        }
    }
}

// ---------------------------------------------------------------------------
// K2: exact rescan (verified R12: block per flagged row, 8 waves x 64 codes,
// grid-stride for robustness).
// ---------------------------------------------------------------------------
__global__ __launch_bounds__(512) void vq_rescan(
    const float* __restrict__ z,
    const float* __restrict__ embT,
    const float* __restrict__ s2g,
    const unsigned* __restrict__ list,
    const unsigned* __restrict__ ctr,
    int* __restrict__ idxflag)
{
    __shared__ unsigned long long wbest[8];
    const int tid  = threadIdx.x;
    const int wid  = tid >> 6;
    const int lane = tid & 63;
    const unsigned count = ctr[0];

    for (unsigned i = blockIdx.x; i < count; i += gridDim.x) {
        const int row = (int)list[i];

        const float x  = z[(size_t)row * VQ_D + lane];
        const float sq = __fmul_rn(x, x);

        float r[8];
#pragma unroll
        for (int j = 0; j < 8; ++j) r[j] = __shfl(sq, j, 64);
#pragma unroll
        for (int it = 1; it < 8; ++it) {
#pragma unroll
            for (int j = 0; j < 8; ++j)
                r[j] = __fadd_rn(r[j], __shfl(sq, it * 8 + j, 64));
        }
        const float s1 = __fadd_rn(
            __fadd_rn(__fadd_rn(r[0], r[1]), __fadd_rn(r[2], r[3])),
            __fadd_rn(__fadd_rn(r[4], r[5]), __fadd_rn(r[6], r[7])));

        const int c = wid * 64 + lane;
        float a = 0.f;
#pragma unroll
        for (int d = 0; d < VQ_D; ++d)
            a = fmaf(__shfl(x, d, 64), embT[d * VQ_K + c], a);

        const float tv = __fadd_rn(__fsub_rn(s1, __fmul_rn(2.0f, a)), s2g[c]);
        unsigned long long best =
            (((unsigned long long)__float_as_uint(tv)) << 32) | (unsigned)c;
#pragma unroll
        for (int m = 1; m <= 32; m <<= 1) {
            const unsigned long long o = __shfl_xor(best, m, 64);
            best = (o < best) ? o : best;
        }
        if (lane == 0) wbest[wid] = best;
        __syncthreads();
        if (tid == 0) {
            unsigned long long b = wbest[0];
#pragma unroll
            for (int w = 1; w < 8; ++w) b = (wbest[w] < b) ? wbest[w] : b;
            idxflag[row] = (int)(b & 0x1FFull);
        }
        __syncthreads();
    }
}

// ---------------------------------------------------------------------------
// K3: streaming epilogue (verified R9-R12). 4 lanes/row, full-line r/w.
// ---------------------------------------------------------------------------
__global__ __launch_bounds__(256) void vq_epilogue(
    const float* __restrict__ z,
    const float* __restrict__ emb,
    const int* __restrict__ idxflag,
    float* __restrict__ zq_out,
    float* __restrict__ idx_out,
    double* __restrict__ partials)
{
    __shared__ double wsum[4];
    const int tid  = threadIdx.x;
    const int row  = blockIdx.x * 64 + (tid >> 2);
    const int seg  = tid & 3;
    const int idx  = idxflag[row] & 0x1FF;

    const float* zp = z + (size_t)row * VQ_D + seg * 16;
    const float* ep = emb + (size_t)idx * VQ_D + seg * 16;
    float* qp = zq_out + (size_t)row * VQ_D + seg * 16;

    double lsum = 0.0;
#pragma unroll
    for (int i = 0; i < 4; ++i) {
        const f32x4 zv = *reinterpret_cast<const f32x4*>(zp + i * 4);
        const f32x4 ev = *reinterpret_cast<const f32x4*>(ep + i * 4);
        f32x4 ov;
#pragma unroll
        for (int j = 0; j < 4; ++j) {
            const float d = __fsub_rn(ev[j], zv[j]);
            ov[j] = __fadd_rn(zv[j], d);
            lsum += (double)__fmul_rn(d, d);
        }
        *reinterpret_cast<f32x4*>(qp + i * 4) = ov;
    }
    if (seg == 0) idx_out[row] = (float)idx;

#pragma unroll
    for (int off = 32; off > 0; off >>= 1)
        lsum += __shfl_down(lsum, off, 64);
    const int lane = tid & 63, w = tid >> 6;
    if (lane == 0) wsum[w] = lsum;
    __syncthreads();
    if (tid == 0)
        partials[blockIdx.x] = wsum[0] + wsum[1] + wsum[2] + wsum[3];
}

// ---------------------------------------------------------------------------
// K4: reduce partials -> loss = 1.25 * sum / N.
// ---------------------------------------------------------------------------
__global__ __launch_bounds__(256) void vq_finalize_kernel(
    const double* __restrict__ partials, int nparts,
    float* __restrict__ loss_out, double inv_n)
{
    __shared__ double ws[4];
    double s = 0.0;
    for (int i = threadIdx.x; i < nparts; i += 256) s += partials[i];
#pragma unroll
    for (int off = 32; off > 0; off >>= 1)
        s += __shfl_down(s, off, 64);
    const int lane = threadIdx.x & 63, w = threadIdx.x >> 6;
    if (lane == 0) ws[w] = s;
    __syncthreads();
    if (threadIdx.x == 0)
        loss_out[0] = (float)(1.25 * (ws[0] + ws[1] + ws[2] + ws[3]) * inv_n);
}

// ---------------------------------------------------------------------------
// Fallback (proven R2 kernel) if ws too small.
// ---------------------------------------------------------------------------
__global__ __launch_bounds__(256) void vq_main_kernel(
    const float* __restrict__ z, const float* __restrict__ emb,
    float* __restrict__ zq_out, float* __restrict__ idx_out,
    double* __restrict__ partials, int rows, int use_atomic)
{
    __shared__ float s2[VQ_K];
    __shared__ double wsb[4];
    for (int k = threadIdx.x; k < VQ_K; k += 256)
        s2[k] = np_sumsq64_g(emb + (size_t)k * VQ_D);
    __syncthreads();
    const int row = blockIdx.x * 256 + threadIdx.x;
    double lsum = 0.0;
    if (row < rows) {
        float zr[VQ_D];
        const float* zp = z + (size_t)row * VQ_D;
#pragma unroll
        for (int d = 0; d < VQ_D; d += 4) {
            const float4 v = *reinterpret_cast<const float4*>(zp + d);
            zr[d] = v.x; zr[d+1] = v.y; zr[d+2] = v.z; zr[d+3] = v.w;
        }
        const float s1 = np_sumsq64_g(zr);
        float best = 3.4e38f; int bi = 0;
        for (int k = 0; k < VQ_K; k += 4) {
            const float* e0 = emb + (size_t)(k+0) * VQ_D;
            const float* e1 = emb + (size_t)(k+1) * VQ_D;
            const float* e2 = emb + (size_t)(k+2) * VQ_D;
            const float* e3 = emb + (size_t)(k+3) * VQ_D;
            float a0=0.f,a1=0.f,a2=0.f,a3=0.f;
#pragma unroll
            for (int d = 0; d < VQ_D; ++d) {
                const float zd = zr[d];
                a0 = fmaf(zd, e0[d], a0); a1 = fmaf(zd, e1[d], a1);
                a2 = fmaf(zd, e2[d], a2); a3 = fmaf(zd, e3[d], a3);
            }
            float t;
            t = __fadd_rn(__fsub_rn(s1, __fmul_rn(2.0f, a0)), s2[k+0]);
            if (t < best) { best = t; bi = k+0; }
            t = __fadd_rn(__fsub_rn(s1, __fmul_rn(2.0f, a1)), s2[k+1]);
            if (t < best) { best = t; bi = k+1; }
            t = __fadd_rn(__fsub_rn(s1, __fmul_rn(2.0f, a2)), s2[k+2]);
            if (t < best) { best = t; bi = k+2; }
            t = __fadd_rn(__fsub_rn(s1, __fmul_rn(2.0f, a3)), s2[k+3]);
            if (t < best) { best = t; bi = k+3; }
        }
        const float* eb = emb + (size_t)bi * VQ_D;
        float* zq = zq_out + (size_t)row * VQ_D;
#pragma unroll
        for (int d = 0; d < VQ_D; d += 4) {
            float4 ev, ov;
            ev.x = eb[d]; ev.y = eb[d+1]; ev.z = eb[d+2]; ev.w = eb[d+3];
            const float d0 = __fsub_rn(ev.x, zr[d]);
            const float d1 = __fsub_rn(ev.y, zr[d+1]);
            const float d2 = __fsub_rn(ev.z, zr[d+2]);
            const float d3 = __fsub_rn(ev.w, zr[d+3]);
            ov.x = __fadd_rn(zr[d], d0);   ov.y = __fadd_rn(zr[d+1], d1);
            ov.z = __fadd_rn(zr[d+2], d2); ov.w = __fadd_rn(zr[d+3], d3);
            *reinterpret_cast<float4*>(zq + d) = ov;
            lsum += (double)__fmul_rn(d0,d0) + (double)__fmul_rn(d1,d1)
                  + (double)__fmul_rn(d2,d2) + (double)__fmul_rn(d3,d3);
        }
        idx_out[row] = (float)bi;
    }
#pragma unroll
    for (int off = 32; off > 0; off >>= 1)
        lsum += __shfl_down(lsum, off, 64);
    const int lane = threadIdx.x & 63, w = threadIdx.x >> 6;
    if (lane == 0) wsb[w] = lsum;
    __syncthreads();
    if (threadIdx.x == 0) {
        const double bs = wsb[0] + wsb[1] + wsb[2] + wsb[3];
        if (use_atomic) atomicAdd(partials, bs);
        else partials[blockIdx.x] = bs;
    }
}

extern "C" void kernel_launch(void* const* d_in, const int* in_sizes, int n_in,
                              void* d_out, int out_size, void* d_ws, size_t ws_size,
                              hipStream_t stream) {
    const float* z   = (const float*)d_in[0];
    const float* emb = (const float*)d_in[1];
    float* out = (float*)d_out;

    const int zn   = in_sizes[0];        // 16777216
    const int rows = zn / VQ_D;          // 262144

    float* zq_out   = out;
    float* loss_out = out + zn;
    float* idx_out  = out + zn + 1;

    const size_t OFF_EBL  = 65536;
    const size_t OFF_S2   = 131072;
    const size_t OFF_EMBT = 133120;
    const size_t OFF_CTR  = 264192;
    const size_t OFF_LIST = 264448;
    const size_t OFF_IDXF = OFF_LIST + (size_t)rows * 4;
    const size_t OFF_PART = OFF_IDXF + (size_t)rows * 4;
    const int eblocks = rows / 64;       // 4096 epilogue blocks
    const size_t need = OFF_PART + (size_t)eblocks * sizeof(double);

    if (ws_size >= need && (rows % 256) == 0) {
        unsigned short* ebh = (unsigned short*)d_ws;
        unsigned short* ebl = (unsigned short*)((char*)d_ws + OFF_EBL);
        float* s2g          = (float*)((char*)d_ws + OFF_S2);
        float* embT         = (float*)((char*)d_ws + OFF_EMBT);
        unsigned* ctr       = (unsigned*)((char*)d_ws + OFF_CTR);
        unsigned* list      = (unsigned*)((char*)d_ws + OFF_LIST);
        int* idxflag        = (int*)((char*)d_ws + OFF_IDXF);
        double* partials    = (double*)((char*)d_ws + OFF_PART);

        vq_prep<<<16, 256, 0, stream>>>(emb, ebh, ebl, s2g, embT, ctr);
        vq_screen2<<<rows / 256, 512, 0, stream>>>(z, ebh, ebl, s2g,
                                                   idxflag, list, ctr);
        vq_rescan<<<8192, 512, 0, stream>>>(z, embT, s2g, list, ctr, idxflag);
        vq_epilogue<<<eblocks, 256, 0, stream>>>(z, emb, idxflag,
                                                 zq_out, idx_out, partials);
        vq_finalize_kernel<<<1, 256, 0, stream>>>(
            partials, eblocks, loss_out, 1.0 / (double)zn);
    } else {
        const int grid = (rows + 255) / 256;
        double* partials = (double*)d_ws;
        const int use_atomic = (ws_size < (size_t)grid * sizeof(double)) ? 1 : 0;
        if (use_atomic) hipMemsetAsync(d_ws, 0, sizeof(double), stream);
        vq_main_kernel<<<grid, 256, 0, stream>>>(z, emb, zq_out, idx_out,
                                                 partials, rows, use_atomic);
        vq_finalize_kernel<<<1, 256, 0, stream>>>(partials, use_atomic ? 1 : grid,
                                                  loss_out, 1.0 / (double)zn);
    }
}

// Round 14
// 152.046 us; speedup vs baseline: 1.4693x; 1.4693x over previous
//
#include <hip/hip_runtime.h>

#define VQ_D 64
#define VQ_K 512
#define W_FLAG 1.0e-4f

typedef float f32x4 __attribute__((ext_vector_type(4)));
typedef short bf16x8 __attribute__((ext_vector_type(8)));

// f32 -> bf16 RNE (no NaN inputs here)
__device__ __forceinline__ unsigned short f2bf(float f) {
    unsigned u = __float_as_uint(f);
    unsigned r = u + 0x7FFFu + ((u >> 16) & 1u);
    return (unsigned short)(r >> 16);
}
__device__ __forceinline__ float bf2f(unsigned short h) {
    return __uint_as_float(((unsigned)h) << 16);
}

// Monotone float->u32 (negatives below positives) — R4 lesson.
__device__ __forceinline__ unsigned ordkey(float f) {
    const unsigned u = __float_as_uint(f);
    return u ^ (unsigned)(((int)u >> 31) | (int)0x80000000);
}
__device__ __forceinline__ float ordkey_inv(unsigned k) {
    const unsigned u = (k & 0x80000000u) ? (k ^ 0x80000000u) : ~k;
    return __uint_as_float(u);
}

// ---------------------------------------------------------------------------
// numpy pairwise_sum replication for n=64 (proven bit-exact in R2).
// Works on any address space (global or LDS) — op order is what matters.
// ---------------------------------------------------------------------------
__device__ __forceinline__ float np_sumsq64_g(const float* __restrict__ x)
{
    float r[8];
#pragma unroll
    for (int j = 0; j < 8; ++j) r[j] = __fmul_rn(x[j], x[j]);
#pragma unroll
    for (int i = 8; i < 64; i += 8) {
#pragma unroll
        for (int j = 0; j < 8; ++j)
            r[j] = __fadd_rn(r[j], __fmul_rn(x[i + j], x[i + j]));
    }
    return __fadd_rn(
        __fadd_rn(__fadd_rn(r[0], r[1]), __fadd_rn(r[2], r[3])),
        __fadd_rn(__fadd_rn(r[4], r[5]), __fadd_rn(r[6], r[7])));
}

// ---------------------------------------------------------------------------
// K0: prep (verified R8-R13): fragment-major bf16 hi/lo split + transposed
// f32 codebook + exact s2. Zeroes the flagged-row counter.
// ---------------------------------------------------------------------------
__global__ __launch_bounds__(256) void vq_prep(
    const float* __restrict__ emb,
    unsigned short* __restrict__ ebh,
    unsigned short* __restrict__ ebl,
    float* __restrict__ s2g,
    float* __restrict__ embT,
    unsigned* __restrict__ ctr)
{
    if (blockIdx.x == 0 && threadIdx.x == 0) ctr[0] = 0u;

    const int tg = blockIdx.x * 256 + threadIdx.x;   // 0..4095
    const int f  = tg >> 6;                          // fragment 0..63
    const int L  = tg & 63;                          // lane slot
    const int c  = (f >> 1) * 16 + (L & 15);         // code
    const int k0 = (f & 1) * 32 + (L >> 4) * 8;      // k base

    const float* e = emb + (size_t)c * VQ_D + k0;
    const f32x4 v0 = *reinterpret_cast<const f32x4*>(e);
    const f32x4 v1 = *reinterpret_cast<const f32x4*>(e + 4);
    bf16x8 h8, l8;
#pragma unroll
    for (int j = 0; j < 8; ++j) {
        const float fv = (j < 4) ? v0[j] : v1[j - 4];
        const unsigned short h = f2bf(fv);
        h8[j] = (short)h;
        l8[j] = (short)f2bf(__fsub_rn(fv, bf2f(h)));
        embT[(k0 + j) * VQ_K + c] = fv;              // transposed f32 copy
    }
    reinterpret_cast<bf16x8*>(ebh)[f * 64 + L] = h8;
    reinterpret_cast<bf16x8*>(ebl)[f * 64 + L] = l8;

    if (blockIdx.x < 2) {
        const int c2 = blockIdx.x * 256 + threadIdx.x;   // 0..511
        s2g[c2] = np_sumsq64_g(emb + (size_t)c2 * VQ_D);
    }
}

// ---------------------------------------------------------------------------
// K1: SCREEN (R13-verified LDS-staged version, unchanged). Fragments staged
// in 128 KB LDS once per block (single barrier), then barrier-free tile loop
// of ds_read_b128 + 12 MFMA per tile. Writes per-row idx to idxflag[];
// appends near-tie rows (gap <= W_FLAG) to list.
// ---------------------------------------------------------------------------
__global__ __launch_bounds__(512) void vq_screen(
    const float* __restrict__ z,
    const unsigned short* __restrict__ ebh,
    const unsigned short* __restrict__ ebl,
    const float* __restrict__ s2g,
    int* __restrict__ idxflag,
    unsigned* __restrict__ list,
    unsigned* __restrict__ ctr)
{
    __shared__ __align__(16) bf16x8 lbh[4096];   // 64 KB
    __shared__ __align__(16) bf16x8 lbl[4096];   // 64 KB
    __shared__ float s2s[VQ_K];

    const int tid  = threadIdx.x;
    const int wid  = tid >> 6;
    const int lane = tid & 63;
    const int l15  = lane & 15;
    const int kg   = lane >> 4;
    const int rowbase = blockIdx.x * 256 + wid * 32;

    {
        const bf16x8* GH = reinterpret_cast<const bf16x8*>(ebh);
        const bf16x8* GL = reinterpret_cast<const bf16x8*>(ebl);
#pragma unroll
        for (int i = 0; i < 8; ++i) {
            lbh[i * 512 + tid] = GH[i * 512 + tid];
            lbl[i * 512 + tid] = GL[i * 512 + tid];
        }
        if (tid < VQ_K) s2s[tid] = s2g[tid];
    }
    __syncthreads();

    bf16x8 Ah[2][2], Al[2][2];
#pragma unroll
    for (int rg = 0; rg < 2; ++rg) {
#pragma unroll
        for (int kc = 0; kc < 2; ++kc) {
            const float* zp = z + (size_t)(rowbase + rg * 16 + l15) * VQ_D
                            + kc * 32 + kg * 8;
            const f32x4 v0 = *reinterpret_cast<const f32x4*>(zp);
            const f32x4 v1 = *reinterpret_cast<const f32x4*>(zp + 4);
            bf16x8 ah, al;
#pragma unroll
            for (int j = 0; j < 8; ++j) {
                const float fv = (j < 4) ? v0[j] : v1[j - 4];
                const unsigned short h = f2bf(fv);
                ah[j] = (short)h;
                al[j] = (short)f2bf(__fsub_rn(fv, bf2f(h)));
            }
            Ah[rg][kc] = ah; Al[rg][kc] = al;
        }
    }

    float m1[2][4], m2[2][4];
    int   i1[2][4];
#pragma unroll
    for (int rg = 0; rg < 2; ++rg)
#pragma unroll
        for (int j = 0; j < 4; ++j) {
            m1[rg][j] = 3.4e38f; m2[rg][j] = 3.4e38f; i1[rg][j] = 0;
        }

#pragma unroll 4
    for (int t = 0; t < 32; ++t) {
        const bf16x8 Bh0 = lbh[(t * 2 + 0) * 64 + lane];
        const bf16x8 Bl0 = lbl[(t * 2 + 0) * 64 + lane];
        const bf16x8 Bh1 = lbh[(t * 2 + 1) * 64 + lane];
        const bf16x8 Bl1 = lbl[(t * 2 + 1) * 64 + lane];
        const float s2v = s2s[t * 16 + l15];
        const int   cid = t * 16 + l15;
#pragma unroll
        for (int rg = 0; rg < 2; ++rg) {
            f32x4 acc = {0.f, 0.f, 0.f, 0.f};
            acc = __builtin_amdgcn_mfma_f32_16x16x32_bf16(Ah[rg][0], Bh0, acc, 0, 0, 0);
            acc = __builtin_amdgcn_mfma_f32_16x16x32_bf16(Ah[rg][0], Bl0, acc, 0, 0, 0);
            acc = __builtin_amdgcn_mfma_f32_16x16x32_bf16(Al[rg][0], Bh0, acc, 0, 0, 0);
            acc = __builtin_amdgcn_mfma_f32_16x16x32_bf16(Ah[rg][1], Bh1, acc, 0, 0, 0);
            acc = __builtin_amdgcn_mfma_f32_16x16x32_bf16(Ah[rg][1], Bl1, acc, 0, 0, 0);
            acc = __builtin_amdgcn_mfma_f32_16x16x32_bf16(Al[rg][1], Bh1, acc, 0, 0, 0);
#pragma unroll
            for (int j = 0; j < 4; ++j) {      // row = kg*4 + j (m89 layout)
                const float tv  = fmaf(-2.0f, acc[j], s2v);
                const float o1  = m1[rg][j];
                m1[rg][j] = fminf(o1, tv);
                i1[rg][j] = (tv < o1) ? cid : i1[rg][j];
                m2[rg][j] = fminf(m2[rg][j], fmaxf(tv, o1));
            }
        }
    }

#pragma unroll
    for (int rg = 0; rg < 2; ++rg) {
        unsigned long long k1[4], k2[4];
#pragma unroll
        for (int j = 0; j < 4; ++j) {
            k1[j] = (((unsigned long long)ordkey(m1[rg][j])) << 32) | (unsigned)i1[rg][j];
            k2[j] = (((unsigned long long)ordkey(m2[rg][j])) << 32) | 0x1FFull;
        }
#pragma unroll
        for (int m = 1; m <= 8; m <<= 1) {
#pragma unroll
            for (int j = 0; j < 4; ++j) {
                const unsigned long long o1 = __shfl_xor(k1[j], m, 64);
                const unsigned long long o2 = __shfl_xor(k2[j], m, 64);
                const unsigned long long lo_ = (k1[j] < o1) ? k1[j] : o1;
                const unsigned long long hi_ = (k1[j] < o1) ? o1 : k1[j];
                const unsigned long long s2m = (k2[j] < o2) ? k2[j] : o2;
                k1[j] = lo_;
                k2[j] = (hi_ < s2m) ? hi_ : s2m;
            }
        }
        if (l15 == 0) {
#pragma unroll
            for (int j = 0; j < 4; ++j) {
                const float t1 = ordkey_inv((unsigned)(k1[j] >> 32));
                const float t2 = ordkey_inv((unsigned)(k2[j] >> 32));
                const int idx = (int)(k1[j] & 0x1FFull);
                const int row = rowbase + rg * 16 + kg * 4 + j;
                idxflag[row] = idx;
                if (__fsub_rn(t2, t1) <= W_FLAG) {
                    const unsigned p = atomicAdd(ctr, 1u);
                    list[p] = (unsigned)row;
                }
            }
        }
    }
}

// ---------------------------------------------------------------------------
// K2: exact rescan — R14: EXACT R12 control flow (one block per flagged row,
// early return; R13's grid-stride variant regressed 45->100us, reverted) +
// one change: z row staged in LDS, s1 computed via the VERIFIED np_sumsq64_g
// on the LDS pointer (bit-identical values & op order), d-loop reads zs[d]
// as uniform-broadcast ds_read (replaces 128 serial lane-shuffles per wave).
// c = tid (512 threads = 512 codes), same key/merge as R12.
// ---------------------------------------------------------------------------
__global__ __launch_bounds__(512) void vq_rescan(
    const float* __restrict__ z,
    const float* __restrict__ embT,
    const float* __restrict__ s2g,
    const unsigned* __restrict__ list,
    const unsigned* __restrict__ ctr,
    int* __restrict__ idxflag)
{
    __shared__ __align__(16) float zs[VQ_D];
    __shared__ unsigned long long wbest[8];
    const int tid  = threadIdx.x;
    const int wid  = tid >> 6;
    const int lane = tid & 63;
    const unsigned count = ctr[0];
    const unsigned i = blockIdx.x;       // one block per flagged row
    if (i >= count) return;

    const int row = (int)list[i];
    if (tid < VQ_D) zs[tid] = z[(size_t)row * VQ_D + tid];
    __syncthreads();

    // Exact numpy pairwise s1 from LDS (same function, same op order).
    const float s1 = np_sumsq64_g(zs);

    // One code per thread: c = tid. Coalesced embT loads (consecutive tid ->
    // consecutive floats); zs[d] is a uniform ds_read broadcast. Sequential-d
    // fmaf chain = bit-exact BLAS k-order (verified R2/R8/R12).
    const int c = tid;
    float a = 0.f;
#pragma unroll
    for (int d = 0; d < VQ_D; ++d)
        a = fmaf(zs[d], embT[d * VQ_K + c], a);

    const float tv = __fadd_rn(__fsub_rn(s1, __fmul_rn(2.0f, a)), s2g[c]);
    // tv ~ 64 > 0 always -> raw-bit order fine (proven R2).
    unsigned long long best =
        (((unsigned long long)__float_as_uint(tv)) << 32) | (unsigned)c;
#pragma unroll
    for (int m = 1; m <= 32; m <<= 1) {
        const unsigned long long o = __shfl_xor(best, m, 64);
        best = (o < best) ? o : best;
    }
    if (lane == 0) wbest[wid] = best;
    __syncthreads();
    if (tid == 0) {
        unsigned long long b = wbest[0];
#pragma unroll
        for (int w = 1; w < 8; ++w) b = (wbest[w] < b) ? wbest[w] : b;
        idxflag[row] = (int)(b & 0x1FFull);
    }
}

// ---------------------------------------------------------------------------
// K3: streaming epilogue (verified R9-R13). 4 lanes/row, full-line r/w.
// z_q = fl(z+fl(e-z)), f64 loss partials over f32-rounded squared diffs.
// ---------------------------------------------------------------------------
__global__ __launch_bounds__(256) void vq_epilogue(
    const float* __restrict__ z,
    const float* __restrict__ emb,
    const int* __restrict__ idxflag,
    float* __restrict__ zq_out,
    float* __restrict__ idx_out,
    double* __restrict__ partials)
{
    __shared__ double wsum[4];
    const int tid  = threadIdx.x;
    const int row  = blockIdx.x * 64 + (tid >> 2);
    const int seg  = tid & 3;
    const int idx  = idxflag[row] & 0x1FF;

    const float* zp = z + (size_t)row * VQ_D + seg * 16;
    const float* ep = emb + (size_t)idx * VQ_D + seg * 16;
    float* qp = zq_out + (size_t)row * VQ_D + seg * 16;

    double lsum = 0.0;
#pragma unroll
    for (int i = 0; i < 4; ++i) {
        const f32x4 zv = *reinterpret_cast<const f32x4*>(zp + i * 4);
        const f32x4 ev = *reinterpret_cast<const f32x4*>(ep + i * 4);
        f32x4 ov;
#pragma unroll
        for (int j = 0; j < 4; ++j) {
            const float d = __fsub_rn(ev[j], zv[j]);
            ov[j] = __fadd_rn(zv[j], d);
            lsum += (double)__fmul_rn(d, d);
        }
        *reinterpret_cast<f32x4*>(qp + i * 4) = ov;
    }
    if (seg == 0) idx_out[row] = (float)idx;

#pragma unroll
    for (int off = 32; off > 0; off >>= 1)
        lsum += __shfl_down(lsum, off, 64);
    const int lane = tid & 63, w = tid >> 6;
    if (lane == 0) wsum[w] = lsum;
    __syncthreads();
    if (tid == 0)
        partials[blockIdx.x] = wsum[0] + wsum[1] + wsum[2] + wsum[3];
}

// ---------------------------------------------------------------------------
// K4: reduce partials -> loss = 1.25 * sum / N.
// ---------------------------------------------------------------------------
__global__ __launch_bounds__(256) void vq_finalize_kernel(
    const double* __restrict__ partials, int nparts,
    float* __restrict__ loss_out, double inv_n)
{
    __shared__ double ws[4];
    double s = 0.0;
    for (int i = threadIdx.x; i < nparts; i += 256) s += partials[i];
#pragma unroll
    for (int off = 32; off > 0; off >>= 1)
        s += __shfl_down(s, off, 64);
    const int lane = threadIdx.x & 63, w = threadIdx.x >> 6;
    if (lane == 0) ws[w] = s;
    __syncthreads();
    if (threadIdx.x == 0)
        loss_out[0] = (float)(1.25 * (ws[0] + ws[1] + ws[2] + ws[3]) * inv_n);
}

// ---------------------------------------------------------------------------
// Fallback (proven R2 kernel) if ws too small.
// ---------------------------------------------------------------------------
__global__ __launch_bounds__(256) void vq_main_kernel(
    const float* __restrict__ z, const float* __restrict__ emb,
    float* __restrict__ zq_out, float* __restrict__ idx_out,
    double* __restrict__ partials, int rows, int use_atomic)
{
    __shared__ float s2[VQ_K];
    __shared__ double wsb[4];
    for (int k = threadIdx.x; k < VQ_K; k += 256)
        s2[k] = np_sumsq64_g(emb + (size_t)k * VQ_D);
    __syncthreads();
    const int row = blockIdx.x * 256 + threadIdx.x;
    double lsum = 0.0;
    if (row < rows) {
        float zr[VQ_D];
        const float* zp = z + (size_t)row * VQ_D;
#pragma unroll
        for (int d = 0; d < VQ_D; d += 4) {
            const float4 v = *reinterpret_cast<const float4*>(zp + d);
            zr[d] = v.x; zr[d+1] = v.y; zr[d+2] = v.z; zr[d+3] = v.w;
        }
        const float s1 = np_sumsq64_g(zr);
        float best = 3.4e38f; int bi = 0;
        for (int k = 0; k < VQ_K; k += 4) {
            const float* e0 = emb + (size_t)(k+0) * VQ_D;
            const float* e1 = emb + (size_t)(k+1) * VQ_D;
            const float* e2 = emb + (size_t)(k+2) * VQ_D;
            const float* e3 = emb + (size_t)(k+3) * VQ_D;
            float a0=0.f,a1=0.f,a2=0.f,a3=0.f;
#pragma unroll
            for (int d = 0; d < VQ_D; ++d) {
                const float zd = zr[d];
                a0 = fmaf(zd, e0[d], a0); a1 = fmaf(zd, e1[d], a1);
                a2 = fmaf(zd, e2[d], a2); a3 = fmaf(zd, e3[d], a3);
            }
            float t;
            t = __fadd_rn(__fsub_rn(s1, __fmul_rn(2.0f, a0)), s2[k+0]);
            if (t < best) { best = t; bi = k+0; }
            t = __fadd_rn(__fsub_rn(s1, __fmul_rn(2.0f, a1)), s2[k+1]);
            if (t < best) { best = t; bi = k+1; }
            t = __fadd_rn(__fsub_rn(s1, __fmul_rn(2.0f, a2)), s2[k+2]);
            if (t < best) { best = t; bi = k+2; }
            t = __fadd_rn(__fsub_rn(s1, __fmul_rn(2.0f, a3)), s2[k+3]);
            if (t < best) { best = t; bi = k+3; }
        }
        const float* eb = emb + (size_t)bi * VQ_D;
        float* zq = zq_out + (size_t)row * VQ_D;
#pragma unroll
        for (int d = 0; d < VQ_D; d += 4) {
            float4 ev, ov;
            ev.x = eb[d]; ev.y = eb[d+1]; ev.z = eb[d+2]; ev.w = eb[d+3];
            const float d0 = __fsub_rn(ev.x, zr[d]);
            const float d1 = __fsub_rn(ev.y, zr[d+1]);
            const float d2 = __fsub_rn(ev.z, zr[d+2]);
            const float d3 = __fsub_rn(ev.w, zr[d+3]);
            ov.x = __fadd_rn(zr[d], d0);   ov.y = __fadd_rn(zr[d+1], d1);
            ov.z = __fadd_rn(zr[d+2], d2); ov.w = __fadd_rn(zr[d+3], d3);
            *reinterpret_cast<float4*>(zq + d) = ov;
            lsum += (double)__fmul_rn(d0,d0) + (double)__fmul_rn(d1,d1)
                  + (double)__fmul_rn(d2,d2) + (double)__fmul_rn(d3,d3);
        }
        idx_out[row] = (float)bi;
    }
#pragma unroll
    for (int off = 32; off > 0; off >>= 1)
        lsum += __shfl_down(lsum, off, 64);
    const int lane = threadIdx.x & 63, w = threadIdx.x >> 6;
    if (lane == 0) wsb[w] = lsum;
    __syncthreads();
    if (threadIdx.x == 0) {
        const double bs = wsb[0] + wsb[1] + wsb[2] + wsb[3];
        if (use_atomic) atomicAdd(partials, bs);
        else partials[blockIdx.x] = bs;
    }
}

extern "C" void kernel_launch(void* const* d_in, const int* in_sizes, int n_in,
                              void* d_out, int out_size, void* d_ws, size_t ws_size,
                              hipStream_t stream) {
    const float* z   = (const float*)d_in[0];
    const float* emb = (const float*)d_in[1];
    float* out = (float*)d_out;

    const int zn   = in_sizes[0];        // 16777216
    const int rows = zn / VQ_D;          // 262144

    float* zq_out   = out;
    float* loss_out = out + zn;
    float* idx_out  = out + zn + 1;

    const size_t OFF_EBL  = 65536;
    const size_t OFF_S2   = 131072;
    const size_t OFF_EMBT = 133120;
    const size_t OFF_CTR  = 264192;
    const size_t OFF_LIST = 264448;
    const size_t OFF_IDXF = OFF_LIST + (size_t)rows * 4;
    const size_t OFF_PART = OFF_IDXF + (size_t)rows * 4;
    const int eblocks = rows / 64;       // 4096 epilogue blocks
    const size_t need = OFF_PART + (size_t)eblocks * sizeof(double);

    if (ws_size >= need && (rows % 256) == 0) {
        unsigned short* ebh = (unsigned short*)d_ws;
        unsigned short* ebl = (unsigned short*)((char*)d_ws + OFF_EBL);
        float* s2g          = (float*)((char*)d_ws + OFF_S2);
        float* embT         = (float*)((char*)d_ws + OFF_EMBT);
        unsigned* ctr       = (unsigned*)((char*)d_ws + OFF_CTR);
        unsigned* list      = (unsigned*)((char*)d_ws + OFF_LIST);
        int* idxflag        = (int*)((char*)d_ws + OFF_IDXF);
        double* partials    = (double*)((char*)d_ws + OFF_PART);

        vq_prep<<<16, 256, 0, stream>>>(emb, ebh, ebl, s2g, embT, ctr);
        vq_screen<<<rows / 256, 512, 0, stream>>>(z, ebh, ebl, s2g,
                                                  idxflag, list, ctr);
        vq_rescan<<<8192, 512, 0, stream>>>(z, embT, s2g, list, ctr, idxflag);
        vq_epilogue<<<eblocks, 256, 0, stream>>>(z, emb, idxflag,
                                                 zq_out, idx_out, partials);
        vq_finalize_kernel<<<1, 256, 0, stream>>>(
            partials, eblocks, loss_out, 1.0 / (double)zn);
    } else {
        const int grid = (rows + 255) / 256;
        double* partials = (double*)d_ws;
        const int use_atomic = (ws_size < (size_t)grid * sizeof(double)) ? 1 : 0;
        if (use_atomic) hipMemsetAsync(d_ws, 0, sizeof(double), stream);
        vq_main_kernel<<<grid, 256, 0, stream>>>(z, emb, zq_out, idx_out,
                                                 partials, rows, use_atomic);
        vq_finalize_kernel<<<1, 256, 0, stream>>>(partials, use_atomic ? 1 : grid,
                                                  loss_out, 1.0 / (double)zn);
    }
}